// Round 6
// baseline (34.610 us; speedup 1.0000x reference)
//
#include <hip/hip_runtime.h>
#include <hip/hip_bf16.h>

// Problem: B=512, D=128, H=512.
// out[a,b] = W2 . relu( x[a]@W1x + y[b]@W1y + b1 ) + b2
// relu(t) = (t+|t|)/2  =>  with U[a,h]=x[a]@W1x+b1, V[b,h]=y[b]@W1y:
//   out[a,b] = b2 + P[a] + Q[b] + 0.5*sum_h |U[a,h]+V[b,h]|*W2[h]
// 3 kernels, forward dataflow only. Fixed ~21us harness overhead measured
// (R2/R5 structure-insensitivity); this round minimizes real kernel work.

#define B 512
#define D 128
#define H 512
#define CH 64      // h-chunk staged in LDS per K2 iteration
#define LDP 68     // padded LDS row stride
#define S 4        // split-K planes in K2

// ---------------- K1: U = x@W1x + b1, V = y@W1y, P/Q ----------------------
// grid (B/4, 2), block 256. Block: 4 rows x full H. Thread: p = t>>7 d-parity,
// s4 = t&127 -> h = 4*s4 (float4 of h). 64 iters x (1 dwordx4 + 16 fma).
__global__ __launch_bounds__(256) void k1_uv(
        const float* __restrict__ x, const float* __restrict__ y,
        const float* __restrict__ W1, const float* __restrict__ b1,
        const float* __restrict__ W2,
        float* __restrict__ U, float* __restrict__ V, float* __restrict__ PQ) {
    const int m  = blockIdx.y;
    const int a0 = blockIdx.x * 4;
    const int t  = threadIdx.x;
    const int p  = t >> 7;        // d parity
    const int s4 = t & 127;       // h-float4 slot
    const int h  = s4 * 4;

    const float* __restrict__ src = (m == 0) ? x : y;
    float* __restrict__ dst       = (m == 0) ? U : V;
    const float* __restrict__ Wm  = W1 + (size_t)m * D * H;

    __shared__ float xs[4][D];
    __shared__ float mred[16][128];
    __shared__ float red2[2][4];

    for (int i = t; i < 4 * D; i += 256)
        xs[i >> 7][i & (D - 1)] = src[(size_t)(a0 + (i >> 7)) * D + (i & (D - 1))];
    __syncthreads();

    float acc[4][4] = {};
#pragma unroll 8
    for (int dd = 0; dd < D; dd += 2) {
        const int d = dd + p;
        const float4 w4 = *(const float4*)(Wm + (size_t)d * H + h);
#pragma unroll
        for (int r = 0; r < 4; ++r) {
            const float xv = xs[r][d];
            acc[r][0] = fmaf(xv, w4.x, acc[r][0]);
            acc[r][1] = fmaf(xv, w4.y, acc[r][1]);
            acc[r][2] = fmaf(xv, w4.z, acc[r][2]);
            acc[r][3] = fmaf(xv, w4.w, acc[r][3]);
        }
    }

    // merge d-parities: p==1 publishes, p==0 adds
    if (p == 1)
#pragma unroll
        for (int r = 0; r < 4; ++r)
#pragma unroll
            for (int c = 0; c < 4; ++c) mred[r * 4 + c][s4] = acc[r][c];
    __syncthreads();

    if (p == 0) {
#pragma unroll
        for (int r = 0; r < 4; ++r)
#pragma unroll
            for (int c = 0; c < 4; ++c) acc[r][c] += mred[r * 4 + c][s4];
        if (m == 0) {
            const float4 bb = *(const float4*)(b1 + h);
#pragma unroll
            for (int r = 0; r < 4; ++r) {
                acc[r][0] += bb.x; acc[r][1] += bb.y;
                acc[r][2] += bb.z; acc[r][3] += bb.w;
            }
        }
#pragma unroll
        for (int r = 0; r < 4; ++r) {
            float4 o; o.x = acc[r][0]; o.y = acc[r][1]; o.z = acc[r][2]; o.w = acc[r][3];
            *(float4*)(dst + (size_t)(a0 + r) * H + h) = o;
        }
        // P/Q: v[r] = sum_h acc*0.5*W2
        const float4 w2 = *(const float4*)(W2 + h);
        float v[4];
#pragma unroll
        for (int r = 0; r < 4; ++r)
            v[r] = 0.5f * (acc[r][0] * w2.x + acc[r][1] * w2.y +
                           acc[r][2] * w2.z + acc[r][3] * w2.w);
#pragma unroll
        for (int r = 0; r < 4; ++r)
            for (int o = 32; o > 0; o >>= 1) v[r] += __shfl_down(v[r], o);
        if ((t & 63) == 0)
#pragma unroll
            for (int r = 0; r < 4; ++r) red2[t >> 6][r] = v[r];
    }
    __syncthreads();
    if (t < 4) PQ[(size_t)m * B + a0 + t] = red2[0][t] + red2[1][t];
}

// ---------------- K2: Pp[z][a,b] = sum_{h slice} |U+V| * (0.5*W2) ----------
// grid (8, 8, S), block 256, 64x64 tile, 4x4/thread, hcount = H/S.
__global__ __launch_bounds__(256) void k2_pair(
        const float* __restrict__ U, const float* __restrict__ V,
        const float* __restrict__ W2, float* __restrict__ Pp, int hcount) {
    __shared__ float Us[CH][LDP];
    __shared__ float Vs[CH][LDP];
    __shared__ float w2s[CH];

    const int a0 = blockIdx.x * 64;
    const int b0 = blockIdx.y * 64;
    const int h0 = blockIdx.z * hcount;
    const int t  = threadIdx.x;
    const int ta = t & 15;
    const int tb = t >> 4;
    const int r  = t >> 2;
    const int q  = t & 3;

    float acc[4][4] = {};

    for (int c = 0; c < hcount; c += CH) {
        const float* __restrict__ Urow = U + (size_t)(a0 + r) * H + h0 + c;
        const float* __restrict__ Vrow = V + (size_t)(b0 + r) * H + h0 + c;
#pragma unroll
        for (int pp = 0; pp < 4; ++pp) {
            const int hh = 4 * q + 16 * pp;
            const float4 u4 = *(const float4*)(Urow + hh);
            const float4 v4 = *(const float4*)(Vrow + hh);
            Us[hh + 0][r] = u4.x; Us[hh + 1][r] = u4.y;
            Us[hh + 2][r] = u4.z; Us[hh + 3][r] = u4.w;
            Vs[hh + 0][r] = v4.x; Vs[hh + 1][r] = v4.y;
            Vs[hh + 2][r] = v4.z; Vs[hh + 3][r] = v4.w;
        }
        if (t < CH) w2s[t] = 0.5f * W2[h0 + c + t];
        __syncthreads();

#pragma unroll 4
        for (int hh = 0; hh < CH; ++hh) {
            const float w = w2s[hh];
            const float4 ua = *(const float4*)&Us[hh][4 * ta];
            const float4 vb = *(const float4*)&Vs[hh][4 * tb];
            const float u[4] = {ua.x, ua.y, ua.z, ua.w};
            const float v[4] = {vb.x, vb.y, vb.z, vb.w};
#pragma unroll
            for (int i = 0; i < 4; ++i)
#pragma unroll
                for (int j = 0; j < 4; ++j)
                    acc[i][j] = fmaf(__builtin_fabsf(u[i] + v[j]), w, acc[i][j]);
        }
        __syncthreads();
    }

    float* __restrict__ outp = Pp + (size_t)blockIdx.z * (B * B);
#pragma unroll
    for (int i = 0; i < 4; ++i) {
        float4 o;
        o.x = acc[i][0]; o.y = acc[i][1]; o.z = acc[i][2]; o.w = acc[i][3];
        *(float4*)(outp + (size_t)(a0 + 4 * ta + i) * B + b0 + 4 * tb) = o;
    }
}

// ---------------- K3: out = b2 + P[a] + Q[b] + sum_z Pp -------------------
__global__ __launch_bounds__(256) void k3_reduce(
        const float* __restrict__ Pp, const float* __restrict__ PQ,
        const float* __restrict__ b2, float* __restrict__ out) {
    const int gi = blockIdx.x * 256 + threadIdx.x;
    const int i = gi * 4;
    const int a = i >> 9;
    const int b = i & (B - 1);

    float4 s = {0.f, 0.f, 0.f, 0.f};
#pragma unroll
    for (int z = 0; z < S; ++z) {
        const float4 p = *(const float4*)(Pp + (size_t)z * (B * B) + i);
        s.x += p.x; s.y += p.y; s.z += p.z; s.w += p.w;
    }
    const float pa = PQ[a] + b2[0];
    const float4 qb = *(const float4*)(PQ + B + b);
    float4 o;
    o.x = pa + qb.x + s.x;
    o.y = pa + qb.y + s.y;
    o.z = pa + qb.z + s.z;
    o.w = pa + qb.w + s.w;
    *(float4*)(out + i) = o;
}

extern "C" void kernel_launch(void* const* d_in, const int* in_sizes, int n_in,
                              void* d_out, int out_size, void* d_ws, size_t ws_size,
                              hipStream_t stream) {
    const float* x  = (const float*)d_in[0];
    const float* y  = (const float*)d_in[1];
    const float* W1 = (const float*)d_in[2];
    const float* b1 = (const float*)d_in[3];
    const float* W2 = (const float*)d_in[4];
    const float* b2 = (const float*)d_in[5];
    float* out = (float*)d_out;

    float* U  = (float*)d_ws;                 // B*H floats = 1 MB
    float* V  = U + (size_t)B * H;            // 1 MB
    float* PQ = V + (size_t)B * H;            // 2*B floats (P then Q)
    float* Pp = PQ + 2 * B;                   // S planes of B*B = 4 MB

    k1_uv<<<dim3(B / 4, 2), 256, 0, stream>>>(x, y, W1, b1, W2, U, V, PQ);
    k2_pair<<<dim3(8, 8, S), 256, 0, stream>>>(U, V, W2, Pp, H / S);
    k3_reduce<<<dim3((B * B) / (256 * 4)), 256, 0, stream>>>(Pp, PQ, b2, out);
}

// Round 7
// 31.648 us; speedup vs baseline: 1.0936x; 1.0936x over previous
//
#include <hip/hip_runtime.h>
#include <hip/hip_bf16.h>

// Problem: B=512, D=128, H=512.
// out[a,b] = W2 . relu( x[a]@W1x + y[b]@W1y + b1 ) + b2
// relu(t) = (t+|t|)/2  =>  with U[a,h]=x[a]@W1x+b1, V[b,h]=y[b]@W1y:
//   out[a,b] = b2 + P[a] + Q[b] + 0.5*sum_h |U[a,h]+V[b,h]|*W2[h]
// R2 topology (measured best, 31.7us): K1 -> K2(S=8) -> K3.
// This round: only K1 changed (8 rows/block -> W1 L2 traffic 64->32 MB,
// 8 FMA per LDS-broadcast read instead of 4). K2/K3 are R2 verbatim.

#define B 512
#define D 128
#define H 512
#define CH 64      // h-chunk staged in LDS per K2 iteration
#define LDP 68     // padded LDS row stride
#define S 8        // split-K planes in K2 (2 blocks/CU — proven best)

// ---------------- K1: U = x@W1x + b1, V = y@W1y, P/Q partials --------------
// grid (B/8, 2, 2), block 256. y: m (0->U from x, 1->V from y); z: h-half.
// Thread computes 8 rows x 1 h (h = z*256 + tid).
__global__ __launch_bounds__(256) void k1_uv(
        const float* __restrict__ x, const float* __restrict__ y,
        const float* __restrict__ W1, const float* __restrict__ b1,
        const float* __restrict__ W2,
        float* __restrict__ U, float* __restrict__ V, float* __restrict__ PQ) {
    const int m  = blockIdx.y;
    const int z  = blockIdx.z;
    const int a0 = blockIdx.x * 8;
    const int t  = threadIdx.x;

    const float* __restrict__ src = (m == 0) ? x : y;
    float* __restrict__ dst       = (m == 0) ? U : V;
    const float* __restrict__ Wm  = W1 + (size_t)m * D * H;

    __shared__ float xs[8][D];
    __shared__ float red[4][8];

    {   // stage 8 input rows (1024 floats) as one float4 per thread
        const int i = t * 4;
        const int r = i >> 7, c = i & (D - 1);
        *(float4*)&xs[r][c] = *(const float4*)(src + (size_t)(a0 + r) * D + c);
    }
    __syncthreads();

    const int h = z * 256 + t;
    const float bias = (m == 0) ? b1[h] : 0.0f;
    float acc[8] = {bias, bias, bias, bias, bias, bias, bias, bias};
#pragma unroll 8
    for (int d = 0; d < D; ++d) {
        const float w = Wm[(size_t)d * H + h];
#pragma unroll
        for (int r = 0; r < 8; ++r) acc[r] = fmaf(xs[r][d], w, acc[r]);
    }
#pragma unroll
    for (int r = 0; r < 8; ++r) dst[(size_t)(a0 + r) * H + h] = acc[r];

    // P/Q partial for this h-slice: sum_h acc_r * (0.5*W2[h])
    const float wp = 0.5f * W2[h];
    float v[8];
#pragma unroll
    for (int r = 0; r < 8; ++r) v[r] = acc[r] * wp;
#pragma unroll
    for (int r = 0; r < 8; ++r)
        for (int o = 32; o > 0; o >>= 1) v[r] += __shfl_down(v[r], o);
    const int wave = t >> 6;
    if ((t & 63) == 0)
#pragma unroll
        for (int r = 0; r < 8; ++r) red[wave][r] = v[r];
    __syncthreads();
    if (t < 8) {
        const float s = red[0][t] + red[1][t] + red[2][t] + red[3][t];
        PQ[(size_t)(m * 2 + z) * B + a0 + t] = s;
    }
}

// ---------------- K2: Pz[a,b] = sum_{h in slice z} |U+V| * W2 --------------
// grid (8, 8, S), block 256. 64x64 output tile; each thread 4x4 outputs.
__global__ __launch_bounds__(256) void k2_pair(
        const float* __restrict__ U, const float* __restrict__ V,
        const float* __restrict__ W2, float* __restrict__ P, int hcount) {
    __shared__ float Us[CH][LDP];
    __shared__ float Vs[CH][LDP];

    const int a0 = blockIdx.x * 64;
    const int b0 = blockIdx.y * 64;
    const int h0 = blockIdx.z * hcount;
    const int tid = threadIdx.x;
    const int ta = tid & 15;   // a-quad
    const int tb = tid >> 4;   // b-quad
    const int r = tid >> 2;    // staging row 0..63
    const int q = tid & 3;     // staging h-quad

    float acc[4][4] = {};

    for (int c = 0; c < hcount; c += CH) {
        const float* __restrict__ Urow = U + (size_t)(a0 + r) * H + h0 + c;
        const float* __restrict__ Vrow = V + (size_t)(b0 + r) * H + h0 + c;
#pragma unroll
        for (int p = 0; p < 4; ++p) {
            const int hh = 4 * q + 16 * p;
            const float4 u4 = *(const float4*)(Urow + hh);
            const float4 v4 = *(const float4*)(Vrow + hh);
            Us[hh + 0][r] = u4.x; Us[hh + 1][r] = u4.y;
            Us[hh + 2][r] = u4.z; Us[hh + 3][r] = u4.w;
            Vs[hh + 0][r] = v4.x; Vs[hh + 1][r] = v4.y;
            Vs[hh + 2][r] = v4.z; Vs[hh + 3][r] = v4.w;
        }
        __syncthreads();

#pragma unroll 4
        for (int hh = 0; hh < CH; ++hh) {
            const float w = W2[h0 + c + hh];      // uniform -> scalar load
            const float4 ua = *(const float4*)&Us[hh][4 * ta];
            const float4 vb = *(const float4*)&Vs[hh][4 * tb];
            const float u[4] = {ua.x, ua.y, ua.z, ua.w};
            const float v[4] = {vb.x, vb.y, vb.z, vb.w};
#pragma unroll
            for (int i = 0; i < 4; ++i)
#pragma unroll
                for (int j = 0; j < 4; ++j)
                    acc[i][j] = fmaf(__builtin_fabsf(u[i] + v[j]), w, acc[i][j]);
        }
        __syncthreads();
    }

    float* __restrict__ out = P + (size_t)blockIdx.z * (B * B);
#pragma unroll
    for (int i = 0; i < 4; ++i) {
        float4 o;
        o.x = acc[i][0]; o.y = acc[i][1]; o.z = acc[i][2]; o.w = acc[i][3];
        *(float4*)(out + (size_t)(a0 + 4 * ta + i) * B + b0 + 4 * tb) = o;
    }
}

// ---------------- K3: out = b2 + P[a] + Q[b] + 0.5 * sum_z Pz --------------
__global__ __launch_bounds__(256) void k3_reduce(
        const float* __restrict__ Pp, const float* __restrict__ PQ,
        const float* __restrict__ b2, float* __restrict__ out) {
    const int gi = blockIdx.x * 256 + threadIdx.x;   // float4 index
    const int i = gi * 4;
    const int a = i >> 9;
    const int b = i & (B - 1);

    float4 s = {0.f, 0.f, 0.f, 0.f};
#pragma unroll
    for (int z = 0; z < S; ++z) {
        const float4 p = *(const float4*)(Pp + (size_t)z * (B * B) + i);
        s.x += p.x; s.y += p.y; s.z += p.z; s.w += p.w;
    }
    const float pa = PQ[a] + PQ[B + a] + b2[0];
    const float4 qb0 = *(const float4*)(PQ + 2 * B + b);
    const float4 qb1 = *(const float4*)(PQ + 3 * B + b);
    float4 o;
    o.x = pa + qb0.x + qb1.x + 0.5f * s.x;
    o.y = pa + qb0.y + qb1.y + 0.5f * s.y;
    o.z = pa + qb0.z + qb1.z + 0.5f * s.z;
    o.w = pa + qb0.w + qb1.w + 0.5f * s.w;
    *(float4*)(out + i) = o;
}

extern "C" void kernel_launch(void* const* d_in, const int* in_sizes, int n_in,
                              void* d_out, int out_size, void* d_ws, size_t ws_size,
                              hipStream_t stream) {
    const float* x  = (const float*)d_in[0];
    const float* y  = (const float*)d_in[1];
    const float* W1 = (const float*)d_in[2];
    const float* b1 = (const float*)d_in[3];
    const float* W2 = (const float*)d_in[4];
    const float* b2 = (const float*)d_in[5];
    float* out = (float*)d_out;

    float* U  = (float*)d_ws;                 // B*H floats = 1 MB
    float* V  = U + (size_t)B * H;            // 1 MB
    float* PQ = V + (size_t)B * H;            // 4*B floats (P halves, Q halves)
    float* Pp = PQ + 4 * B;                   // S planes of B*B = 8 MB

    k1_uv<<<dim3(B / 8, 2, 2), 256, 0, stream>>>(x, y, W1, b1, W2, U, V, PQ);
    k2_pair<<<dim3(8, 8, S), 256, 0, stream>>>(U, V, W2, Pp, H / S);
    k3_reduce<<<dim3((B * B) / (256 * 4)), 256, 0, stream>>>(Pp, PQ, b2, out);
}

// Round 8
// 31.521 us; speedup vs baseline: 1.0980x; 1.0040x over previous
//
#include <hip/hip_runtime.h>
#include <hip/hip_bf16.h>

// Problem: B=512, D=128, H=512.
// out[a,b] = W2 . relu( x[a]@W1x + y[b]@W1y + b1 ) + b2
// relu(t) = (t+|t|)/2  =>  with U[a,h]=x[a]@W1x+b1, V[b,h]=y[b]@W1y:
//   out[a,b] = b2 + P[a] + Q[b] + 0.5*sum_h |U[a,h]+V[b,h]|*W2[h]
// Topology: K1 -> K2(S=4) -> K3. Model: ~22us fixed harness floor +
// kernel work. This round: S=8->4 planes (K3 traffic + flush halved)
// while PRESERVING 2 waves/SIMD in K2 (512-thr blocks, 1 block/CU) —
// R6 showed S-reduction at 1 wave/SIMD regresses.

#define B 512
#define D 128
#define H 512
#define CH 64      // h-chunk staged in LDS per K2 iteration
#define LDP 68     // padded LDS row stride
#define S 4        // split-K planes in K2

// ---------------- K1: U = x@W1x + b1, V = y@W1y, P/Q partials --------------
// grid (B/8, 2, 2), block 256. y: m (0->U from x, 1->V from y); z: h-half.
// Thread computes 8 rows x 1 h (h = z*256 + tid).  (R7 verbatim)
__global__ __launch_bounds__(256) void k1_uv(
        const float* __restrict__ x, const float* __restrict__ y,
        const float* __restrict__ W1, const float* __restrict__ b1,
        const float* __restrict__ W2,
        float* __restrict__ U, float* __restrict__ V, float* __restrict__ PQ) {
    const int m  = blockIdx.y;
    const int z  = blockIdx.z;
    const int a0 = blockIdx.x * 8;
    const int t  = threadIdx.x;

    const float* __restrict__ src = (m == 0) ? x : y;
    float* __restrict__ dst       = (m == 0) ? U : V;
    const float* __restrict__ Wm  = W1 + (size_t)m * D * H;

    __shared__ float xs[8][D];
    __shared__ float red[4][8];

    {   // stage 8 input rows (1024 floats) as one float4 per thread
        const int i = t * 4;
        const int r = i >> 7, c = i & (D - 1);
        *(float4*)&xs[r][c] = *(const float4*)(src + (size_t)(a0 + r) * D + c);
    }
    __syncthreads();

    const int h = z * 256 + t;
    const float bias = (m == 0) ? b1[h] : 0.0f;
    float acc[8] = {bias, bias, bias, bias, bias, bias, bias, bias};
#pragma unroll 8
    for (int d = 0; d < D; ++d) {
        const float w = Wm[(size_t)d * H + h];
#pragma unroll
        for (int r = 0; r < 8; ++r) acc[r] = fmaf(xs[r][d], w, acc[r]);
    }
#pragma unroll
    for (int r = 0; r < 8; ++r) dst[(size_t)(a0 + r) * H + h] = acc[r];

    const float wp = 0.5f * W2[h];
    float v[8];
#pragma unroll
    for (int r = 0; r < 8; ++r) v[r] = acc[r] * wp;
#pragma unroll
    for (int r = 0; r < 8; ++r)
        for (int o = 32; o > 0; o >>= 1) v[r] += __shfl_down(v[r], o);
    const int wave = t >> 6;
    if ((t & 63) == 0)
#pragma unroll
        for (int r = 0; r < 8; ++r) red[wave][r] = v[r];
    __syncthreads();
    if (t < 8) {
        const float s = red[0][t] + red[1][t] + red[2][t] + red[3][t];
        PQ[(size_t)(m * 2 + z) * B + a0 + t] = s;
    }
}

// ---------------- K2: Pz[a,b] = sum_{h in slice z} |U+V| * W2 --------------
// grid (8, 8, S), block 512 (8 waves -> 1 block/CU, 2 waves/SIMD).
// 64x64 tile; hcount = H/S = 128 as two CH=64 chunks; 8 outputs/thread.
__global__ __launch_bounds__(512) void k2_pair(
        const float* __restrict__ U, const float* __restrict__ V,
        const float* __restrict__ W2, float* __restrict__ P) {
    __shared__ float Us[CH][LDP];
    __shared__ float Vs[CH][LDP];

    const int a0 = blockIdx.x * 64;
    const int b0 = blockIdx.y * 64;
    const int h0 = blockIdx.z * (H / S);
    const int t  = threadIdx.x;
    const int ta = t & 15;     // a-quad (4 rows)
    const int tb = t >> 4;     // b-pair (2 cols), 0..31
    const int r  = t >> 3;     // staging row 0..63
    const int q  = t & 7;      // staging f4-slot

    float acc[4][2] = {};

#pragma unroll
    for (int c = 0; c < H / S; c += CH) {
        const float* __restrict__ Urow = U + (size_t)(a0 + r) * H + h0 + c;
        const float* __restrict__ Vrow = V + (size_t)(b0 + r) * H + h0 + c;
#pragma unroll
        for (int p = 0; p < 2; ++p) {
            const int hh = 4 * q + 32 * p;
            const float4 u4 = *(const float4*)(Urow + hh);
            const float4 v4 = *(const float4*)(Vrow + hh);
            Us[hh + 0][r] = u4.x; Us[hh + 1][r] = u4.y;
            Us[hh + 2][r] = u4.z; Us[hh + 3][r] = u4.w;
            Vs[hh + 0][r] = v4.x; Vs[hh + 1][r] = v4.y;
            Vs[hh + 2][r] = v4.z; Vs[hh + 3][r] = v4.w;
        }
        __syncthreads();

#pragma unroll 4
        for (int hh = 0; hh < CH; ++hh) {
            const float w = W2[h0 + c + hh];      // uniform -> scalar load
            const float4 ua = *(const float4*)&Us[hh][4 * ta];
            const float2 vb = *(const float2*)&Vs[hh][2 * tb];
            const float u[4] = {ua.x, ua.y, ua.z, ua.w};
#pragma unroll
            for (int i = 0; i < 4; ++i) {
                acc[i][0] = fmaf(__builtin_fabsf(u[i] + vb.x), w, acc[i][0]);
                acc[i][1] = fmaf(__builtin_fabsf(u[i] + vb.y), w, acc[i][1]);
            }
        }
        __syncthreads();
    }

    float* __restrict__ out = P + (size_t)blockIdx.z * (B * B);
#pragma unroll
    for (int i = 0; i < 4; ++i) {
        float2 o;
        o.x = acc[i][0]; o.y = acc[i][1];
        *(float2*)(out + (size_t)(a0 + 4 * ta + i) * B + b0 + 2 * tb) = o;
    }
}

// ---------------- K3: out = b2 + P[a] + Q[b] + 0.5 * sum_z Pz --------------
__global__ __launch_bounds__(256) void k3_reduce(
        const float* __restrict__ Pp, const float* __restrict__ PQ,
        const float* __restrict__ b2, float* __restrict__ out) {
    const int gi = blockIdx.x * 256 + threadIdx.x;   // float4 index
    const int i = gi * 4;
    const int a = i >> 9;
    const int b = i & (B - 1);

    float4 s = {0.f, 0.f, 0.f, 0.f};
#pragma unroll
    for (int z = 0; z < S; ++z) {
        const float4 p = *(const float4*)(Pp + (size_t)z * (B * B) + i);
        s.x += p.x; s.y += p.y; s.z += p.z; s.w += p.w;
    }
    const float pa = PQ[a] + PQ[B + a] + b2[0];
    const float4 qb0 = *(const float4*)(PQ + 2 * B + b);
    const float4 qb1 = *(const float4*)(PQ + 3 * B + b);
    float4 o;
    o.x = pa + qb0.x + qb1.x + 0.5f * s.x;
    o.y = pa + qb0.y + qb1.y + 0.5f * s.y;
    o.z = pa + qb0.z + qb1.z + 0.5f * s.z;
    o.w = pa + qb0.w + qb1.w + 0.5f * s.w;
    *(float4*)(out + i) = o;
}

extern "C" void kernel_launch(void* const* d_in, const int* in_sizes, int n_in,
                              void* d_out, int out_size, void* d_ws, size_t ws_size,
                              hipStream_t stream) {
    const float* x  = (const float*)d_in[0];
    const float* y  = (const float*)d_in[1];
    const float* W1 = (const float*)d_in[2];
    const float* b1 = (const float*)d_in[3];
    const float* W2 = (const float*)d_in[4];
    const float* b2 = (const float*)d_in[5];
    float* out = (float*)d_out;

    float* U  = (float*)d_ws;                 // B*H floats = 1 MB
    float* V  = U + (size_t)B * H;            // 1 MB
    float* PQ = V + (size_t)B * H;            // 4*B floats (P halves, Q halves)
    float* Pp = PQ + 4 * B;                   // S planes of B*B = 4 MB

    k1_uv<<<dim3(B / 8, 2, 2), 256, 0, stream>>>(x, y, W1, b1, W2, U, V, PQ);
    k2_pair<<<dim3(8, 8, S), 512, 0, stream>>>(U, V, W2, Pp);
    k3_reduce<<<dim3((B * B) / (256 * 4)), 256, 0, stream>>>(Pp, PQ, b2, out);
}